// Round 7
// baseline (400.925 us; speedup 1.0000x reference)
//
#include <hip/hip_runtime.h>
#include <stdint.h>

// region_pooling via scatter + dense GEMM + split-k partials.
// F: [B=8, HW=4096, C=1024] fp32 (H=W=64); pc: [B, M=32, P=512, 2]
// out[b,m,c] = sum_hw W[b][hw][m] * F[b][hw][c]; W = scattered bilinear
// weights pre-scaled by 1/P.
//
// wgemm v5: R6's async global_load_lds double-buffer, re-balanced for
// occupancy. R2-R6 all ran 512 blocks = 2 blocks/CU = <=8 waves/CU; the
// per-round barrier drain was latency-exposed. Now: NKC=64 -> 1024 blocks,
// W staged per-round (1 KB slab, double-buffered) instead of a 16 KB tile
// -> 34 KB LDS -> 4 blocks/CU co-resident, 16 waves/CU.

#define NB 8
#define NM 32
#define NP 512
#define NC 1024
#define NH 64
#define NHW 4096

#define NKC  64                   // k-split: blocks per (ct,b)
#define ROWS (NHW / NKC)          // 64 rows per block
#define KT   8                    // rows per sub-tile
#define NT   (ROWS / KT)          // 8 sub-tiles
#define NCT  2                    // c-tiles of 512 channels
#define CTW  512

__device__ __forceinline__ void async16(const void* g, void* l) {
    __builtin_amdgcn_global_load_lds(
        (const __attribute__((address_space(1))) unsigned int*)g,
        (__attribute__((address_space(3))) unsigned int*)l,
        16, 0, 0);
}

// ---- Phase 1: scatter bilinear weights into W[b][hw][m] (pre-zeroed) ----
__global__ __launch_bounds__(256) void scatter_w(
    const float* __restrict__ pc, float* __restrict__ W)
{
    int idx = blockIdx.x * 256 + threadIdx.x;   // [0, B*M*P)
    int bm  = idx >> 9;                         // b*NM + m
    int m   = bm & (NM - 1);
    int b   = bm >> 5;

    float2 c = ((const float2*)pc)[idx];
    float y = c.x * 63.0f;
    float x = c.y * 63.0f;
    float x0f = floorf(x), y0f = floorf(y);
    float wx = x - x0f, wy = y - y0f;
    int ix0 = min(max((int)x0f, 0), 63);
    int ix1 = min(ix0 + 1, 63);
    int iy0 = min(max((int)y0f, 0), 63);
    int iy1 = min(iy0 + 1, 63);
    float wx1 = 1.0f - wx, wy1 = 1.0f - wy;
    const float s = 1.0f / (float)NP;           // fold the mean here

    float* Wb = W + (size_t)b * (NHW * NM) + m;
    atomicAdd(Wb + ((iy0 * NH + ix0) * NM), wx1 * wy1 * s);
    atomicAdd(Wb + ((iy0 * NH + ix1) * NM), wx  * wy1 * s);
    atomicAdd(Wb + ((iy1 * NH + ix0) * NM), wx1 * wy  * s);
    atomicAdd(Wb + ((iy1 * NH + ix1) * NM), wx  * wy  * s);
}

// ---- Phase 2: P[kc][b][m][c] = sum_{rows of chunk} W[b][hw][m]*F[b][hw][c]
// grid (NKC, NCT, NB) = 1024 blocks; 256 thr = 4 waves; 34 KB LDS -> 4 blk/CU.
// wave w -> m-octet [8w, 8w+8); lane -> channels ct*512 + 4*lane + {0..3,256..259}.
__global__ __launch_bounds__(256, 4) void wgemm(
    const float* __restrict__ W, const float* __restrict__ F,
    float* __restrict__ P)
{
    __shared__ float4 sF[2][KT * CTW / 4];      // 2 x 16 KB (8 rows x 512 ch)
    __shared__ float4 sWd[2][KT * NM / 4];      // 2 x 1 KB (8 rows x 32 m)

    const int kc   = blockIdx.x;
    const int ct   = blockIdx.y;
    const int b    = blockIdx.z;
    const int tid  = threadIdx.x;
    const int wav  = tid >> 6;
    const int lane = tid & 63;
    const int hw0  = kc * ROWS;
    const int wq   = wav * 2;                   // float4 index of m-octet
    const int c0   = ct * CTW + lane * 4;
    const int lane16 = lane * 16;

    const char* Wg = (const char*)(W + ((size_t)b * NHW + hw0) * NM);
    const char* Fg = (const char*)(F + ((size_t)b * NHW + hw0) * NC + ct * CTW);

    // stage sub-tile t into buffer buf: F 16 x 1KB issues + W 1 x 1KB issue
    auto stage = [&](int t, int buf) {
        char* ldsF = (char*)sF[buf];
#pragma unroll
        for (int i = 0; i < 4; ++i) {
            int j   = wav * 4 + i;              // 0..15
            int row = j >> 1, half = j & 1;
            async16(Fg + (size_t)(t * KT + row) * (NC * 4) + half * 1024 + lane16,
                    ldsF + j * 1024 + lane16);
        }
        if (wav == 0)
            async16(Wg + (size_t)t * KT * NM * 4 + lane16,
                    (char*)sWd[buf] + lane16);
    };

    stage(0, 0);
    __syncthreads();                            // drains vmcnt: sub-tile 0

    float4 acc[8][2];
#pragma unroll
    for (int m = 0; m < 8; ++m) {
        acc[m][0] = make_float4(0.f, 0.f, 0.f, 0.f);
        acc[m][1] = make_float4(0.f, 0.f, 0.f, 0.f);
    }

    for (int t = 0; t < NT; ++t) {
        if (t + 1 < NT) stage(t + 1, (t + 1) & 1);   // async, drained at barrier
        const float4* fb = sF[t & 1];
        const float4* wr = sWd[t & 1];
#pragma unroll
        for (int r = 0; r < KT; ++r) {
            float4 f0 = fb[r * 128 + lane];
            float4 f1 = fb[r * 128 + 64 + lane];
            float4 wa = wr[r * 8 + wq];
            float4 wb = wr[r * 8 + wq + 1];
            float wv[8] = {wa.x, wa.y, wa.z, wa.w, wb.x, wb.y, wb.z, wb.w};
#pragma unroll
            for (int m = 0; m < 8; ++m) {
                acc[m][0].x = fmaf(wv[m], f0.x, acc[m][0].x);
                acc[m][0].y = fmaf(wv[m], f0.y, acc[m][0].y);
                acc[m][0].z = fmaf(wv[m], f0.z, acc[m][0].z);
                acc[m][0].w = fmaf(wv[m], f0.w, acc[m][0].w);
                acc[m][1].x = fmaf(wv[m], f1.x, acc[m][1].x);
                acc[m][1].y = fmaf(wv[m], f1.y, acc[m][1].y);
                acc[m][1].z = fmaf(wv[m], f1.z, acc[m][1].z);
                acc[m][1].w = fmaf(wv[m], f1.w, acc[m][1].w);
            }
        }
        __syncthreads();
    }

    // partials: P[kc][b][m][c]
    float* pb = P + (((size_t)kc * NB + b) * NM + wav * 8) * NC + c0;
#pragma unroll
    for (int m = 0; m < 8; ++m) {
        *(float4*)(pb + (size_t)m * NC)       = acc[m][0];
        *(float4*)(pb + (size_t)m * NC + 256) = acc[m][1];
    }
}

// ---- Phase 3: out = sum over the 64 k-chunk partials ----
__global__ __launch_bounds__(256) void reduce_p(
    const float* __restrict__ P, float* __restrict__ out)
{
    const int idx = blockIdx.x * 256 + threadIdx.x;   // [0, NB*NM*NC/4)
    const float4* p4 = (const float4*)P;
    const int stride = NB * NM * NC / 4;              // 65536
    float4 s = make_float4(0.f, 0.f, 0.f, 0.f);
#pragma unroll
    for (int kc = 0; kc < NKC; ++kc) {
        float4 v = p4[(size_t)kc * stride + idx];
        s.x += v.x; s.y += v.y; s.z += v.z; s.w += v.w;
    }
    ((float4*)out)[idx] = s;
}

// ---- Fallback (ws too small): direct gather ----
__global__ __launch_bounds__(256) void region_pool_direct(
    const float* __restrict__ fm, const float* __restrict__ pc,
    float* __restrict__ out)
{
    __shared__ int4   sIdx[NP];
    __shared__ float4 sWv[NP];
    const int bid = blockIdx.x;
    const int b   = bid >> 5;
    const int tid = threadIdx.x;
    const float2* pc2 = (const float2*)(pc + (size_t)bid * NP * 2);
    for (int p = tid; p < NP; p += 256) {
        float2 c = pc2[p];
        float y = c.x * 63.0f, x = c.y * 63.0f;
        float x0f = floorf(x), y0f = floorf(y);
        float wx = x - x0f, wy = y - y0f;
        int ix0 = min(max((int)x0f, 0), 63);
        int ix1 = min(ix0 + 1, 63);
        int iy0 = min(max((int)y0f, 0), 63);
        int iy1 = min(iy0 + 1, 63);
        sIdx[p] = make_int4((iy0 * NH + ix0) << 10, (iy0 * NH + ix1) << 10,
                            (iy1 * NH + ix0) << 10, (iy1 * NH + ix1) << 10);
        float wx1 = 1.0f - wx, wy1 = 1.0f - wy;
        sWv[p] = make_float4(wx1 * wy1, wx * wy1, wx1 * wy, wx * wy);
    }
    __syncthreads();
    const float* Fb = fm + (size_t)b * (NHW * NC) + tid * 4;
    float4 acc = make_float4(0.f, 0.f, 0.f, 0.f);
#pragma unroll 4
    for (int p = 0; p < NP; ++p) {
        int4 off = sIdx[p]; float4 w = sWv[p];
        float4 f00 = *(const float4*)(Fb + off.x);
        float4 f01 = *(const float4*)(Fb + off.y);
        float4 f10 = *(const float4*)(Fb + off.z);
        float4 f11 = *(const float4*)(Fb + off.w);
        acc.x = fmaf(w.x, f00.x, fmaf(w.y, f01.x, fmaf(w.z, f10.x, fmaf(w.w, f11.x, acc.x))));
        acc.y = fmaf(w.x, f00.y, fmaf(w.y, f01.y, fmaf(w.z, f10.y, fmaf(w.w, f11.y, acc.y))));
        acc.z = fmaf(w.x, f00.z, fmaf(w.y, f01.z, fmaf(w.z, f10.z, fmaf(w.w, f11.z, acc.z))));
        acc.w = fmaf(w.x, f00.w, fmaf(w.y, f01.w, fmaf(w.z, f10.w, fmaf(w.w, f11.w, acc.w))));
    }
    const float inv = 1.0f / (float)NP;
    ((float4*)(out + (size_t)bid * NC))[tid] =
        make_float4(acc.x * inv, acc.y * inv, acc.z * inv, acc.w * inv);
}

extern "C" void kernel_launch(void* const* d_in, const int* in_sizes, int n_in,
                              void* d_out, int out_size, void* d_ws, size_t ws_size,
                              hipStream_t stream) {
    const float* fm = (const float*)d_in[0];   // [8, 4096, 1024]
    const float* pc = (const float*)d_in[1];   // [8, 32, 512, 2]
    float* out = (float*)d_out;                // [8, 32, 1, 1024]

    const size_t wbytes = (size_t)NB * NHW * NM * sizeof(float);           // 4 MB
    const size_t pbytes = (size_t)NKC * NB * NM * NC * sizeof(float);      // 64 MB
    if (ws_size >= wbytes + pbytes) {
        float* W = (float*)d_ws;
        float* P = (float*)((char*)d_ws + wbytes);
        hipMemsetAsync(W, 0, wbytes, stream);
        scatter_w<<<(NB * NM * NP) / 256, 256, 0, stream>>>(pc, W);
        dim3 grid(NKC, NCT, NB);
        wgemm<<<grid, 256, 0, stream>>>(W, fm, P);
        reduce_p<<<(NB * NM * NC / 4) / 256, 256, 0, stream>>>(P, out);
    } else {
        region_pool_direct<<<NB * NM, 256, 0, stream>>>(fm, pc, out);
    }
}

// Round 8
// 238.318 us; speedup vs baseline: 1.6823x; 1.6823x over previous
//
#include <hip/hip_runtime.h>
#include <stdint.h>

// region_pooling via scatter + dense GEMM + split-k partials.
// F: [B=8, HW=4096, C=1024] fp32 (H=W=64); pc: [B, M=32, P=512, 2]
// out[b,m,c] = sum_hw W[b][hw][m] * F[b][hw][c]; W = scattered bilinear
// weights pre-scaled by 1/P.
//
// wgemm v6: R6's async global_load_lds double-buffer, made spill-proof.
// R7's regression (WRITE 505 MB ~ 8x P) was scratch spill: forced
// __launch_bounds__(256,4) + 64-float acc. Now acc = 8 m x 1 float4 = 32
// VGPRs (CTW=256, NCT=4), no min-waves bound, 32 KB LDS -> ~5 blocks/CU.

#define NB 8
#define NM 32
#define NP 512
#define NC 1024
#define NH 64
#define NHW 4096

#define NKC  32                   // k-split: blocks per (ct,b)
#define ROWS (NHW / NKC)          // 128 rows per block
#define KT   8                    // rows per sub-tile
#define NT   (ROWS / KT)          // 16 sub-tiles
#define NCT  4                    // c-tiles
#define CTW  256                  // channels per c-tile (1 float4/thread)

__device__ __forceinline__ void async16(const void* g, void* l) {
    __builtin_amdgcn_global_load_lds(
        (const __attribute__((address_space(1))) unsigned int*)g,
        (__attribute__((address_space(3))) unsigned int*)l,
        16, 0, 0);
}

// ---- Phase 1: scatter bilinear weights into W[b][hw][m] (pre-zeroed) ----
__global__ __launch_bounds__(256) void scatter_w(
    const float* __restrict__ pc, float* __restrict__ W)
{
    int idx = blockIdx.x * 256 + threadIdx.x;   // [0, B*M*P)
    int bm  = idx >> 9;                         // b*NM + m
    int m   = bm & (NM - 1);
    int b   = bm >> 5;

    float2 c = ((const float2*)pc)[idx];
    float y = c.x * 63.0f;
    float x = c.y * 63.0f;
    float x0f = floorf(x), y0f = floorf(y);
    float wx = x - x0f, wy = y - y0f;
    int ix0 = min(max((int)x0f, 0), 63);
    int ix1 = min(ix0 + 1, 63);
    int iy0 = min(max((int)y0f, 0), 63);
    int iy1 = min(iy0 + 1, 63);
    float wx1 = 1.0f - wx, wy1 = 1.0f - wy;
    const float s = 1.0f / (float)NP;           // fold the mean here

    float* Wb = W + (size_t)b * (NHW * NM) + m;
    atomicAdd(Wb + ((iy0 * NH + ix0) * NM), wx1 * wy1 * s);
    atomicAdd(Wb + ((iy0 * NH + ix1) * NM), wx  * wy1 * s);
    atomicAdd(Wb + ((iy1 * NH + ix0) * NM), wx1 * wy  * s);
    atomicAdd(Wb + ((iy1 * NH + ix1) * NM), wx  * wy  * s);
}

// ---- Phase 2: P[kc][b][m][c] = sum_{rows of chunk} W[b][hw][m]*F[b][hw][c]
// grid (NKC, NCT, NB) = 1024 blocks; 256 thr = 4 waves; 32 KB LDS.
// wave w -> m-octet [8w, 8w+8); lane -> channels ct*256 + 4*lane.
__global__ __launch_bounds__(256) void wgemm(
    const float* __restrict__ W, const float* __restrict__ F,
    float* __restrict__ P)
{
    __shared__ float4 sF[2][KT * CTW / 4];      // 2 x 8 KB (8 rows x 256 ch)
    __shared__ float4 sWt[ROWS * NM / 4];       // 16 KB (128 rows x 32 m)

    const int kc   = blockIdx.x;
    const int ct   = blockIdx.y;
    const int b    = blockIdx.z;
    const int tid  = threadIdx.x;
    const int wav  = tid >> 6;
    const int lane = tid & 63;
    const int hw0  = kc * ROWS;
    const int wq   = wav * 2;                   // float4 index of m-octet
    const int c0   = ct * CTW + lane * 4;
    const int lane16 = lane * 16;

    const char* Wg = (const char*)(W + ((size_t)b * NHW + hw0) * NM); // 16 KB contig
    const char* Fg = (const char*)(F + ((size_t)b * NHW + hw0) * NC + ct * CTW);

    // stage W tile once: 16 x 1KB wave-issues (4 per wave)
    {
        char* lds = (char*)sWt;
#pragma unroll
        for (int i = 0; i < 4; ++i) {
            int j = wav * 4 + i;
            async16(Wg + j * 1024 + lane16, lds + j * 1024 + lane16);
        }
    }
    // stage F sub-tile t (8 rows x 1 KB) into buffer buf: 8 issues, 2/wave
    auto stage_f = [&](int t, int buf) {
        char* lds = (char*)sF[buf];
#pragma unroll
        for (int i = 0; i < 2; ++i) {
            int j = wav * 2 + i;                // row 0..7
            async16(Fg + (size_t)(t * KT + j) * (NC * 4) + lane16,
                    lds + j * 1024 + lane16);
        }
    };

    stage_f(0, 0);
    __syncthreads();                            // drains vmcnt: W + sub-tile 0

    float4 acc[8];
#pragma unroll
    for (int m = 0; m < 8; ++m) acc[m] = make_float4(0.f, 0.f, 0.f, 0.f);

    for (int t = 0; t < NT; ++t) {
        if (t + 1 < NT) stage_f(t + 1, (t + 1) & 1);  // async, drained at barrier
        const float4* fb = sF[t & 1];
        const float4* wr = sWt + (size_t)(t * KT) * (NM / 4);
#pragma unroll
        for (int r = 0; r < KT; ++r) {
            float4 f  = fb[r * 64 + lane];
            float4 wa = wr[r * 8 + wq];
            float4 wb = wr[r * 8 + wq + 1];
            float wv[8] = {wa.x, wa.y, wa.z, wa.w, wb.x, wb.y, wb.z, wb.w};
#pragma unroll
            for (int m = 0; m < 8; ++m) {
                acc[m].x = fmaf(wv[m], f.x, acc[m].x);
                acc[m].y = fmaf(wv[m], f.y, acc[m].y);
                acc[m].z = fmaf(wv[m], f.z, acc[m].z);
                acc[m].w = fmaf(wv[m], f.w, acc[m].w);
            }
        }
        __syncthreads();
    }

    // partials: P[kc][b][m][c]
    float* pb = P + (((size_t)kc * NB + b) * NM + wav * 8) * NC + c0;
#pragma unroll
    for (int m = 0; m < 8; ++m)
        *(float4*)(pb + (size_t)m * NC) = acc[m];
}

// ---- Phase 3: out = sum over the 32 k-chunk partials ----
__global__ __launch_bounds__(256) void reduce_p(
    const float* __restrict__ P, float* __restrict__ out)
{
    const int idx = blockIdx.x * 256 + threadIdx.x;   // [0, NB*NM*NC/4)
    const float4* p4 = (const float4*)P;
    const int stride = NB * NM * NC / 4;              // 65536
    float4 s = make_float4(0.f, 0.f, 0.f, 0.f);
#pragma unroll
    for (int kc = 0; kc < NKC; ++kc) {
        float4 v = p4[(size_t)kc * stride + idx];
        s.x += v.x; s.y += v.y; s.z += v.z; s.w += v.w;
    }
    ((float4*)out)[idx] = s;
}

// ---- Fallback (ws too small): direct gather ----
__global__ __launch_bounds__(256) void region_pool_direct(
    const float* __restrict__ fm, const float* __restrict__ pc,
    float* __restrict__ out)
{
    __shared__ int4   sIdx[NP];
    __shared__ float4 sWv[NP];
    const int bid = blockIdx.x;
    const int b   = bid >> 5;
    const int tid = threadIdx.x;
    const float2* pc2 = (const float2*)(pc + (size_t)bid * NP * 2);
    for (int p = tid; p < NP; p += 256) {
        float2 c = pc2[p];
        float y = c.x * 63.0f, x = c.y * 63.0f;
        float x0f = floorf(x), y0f = floorf(y);
        float wx = x - x0f, wy = y - y0f;
        int ix0 = min(max((int)x0f, 0), 63);
        int ix1 = min(ix0 + 1, 63);
        int iy0 = min(max((int)y0f, 0), 63);
        int iy1 = min(iy0 + 1, 63);
        sIdx[p] = make_int4((iy0 * NH + ix0) << 10, (iy0 * NH + ix1) << 10,
                            (iy1 * NH + ix0) << 10, (iy1 * NH + ix1) << 10);
        float wx1 = 1.0f - wx, wy1 = 1.0f - wy;
        sWv[p] = make_float4(wx1 * wy1, wx * wy1, wx1 * wy, wx * wy);
    }
    __syncthreads();
    const float* Fb = fm + (size_t)b * (NHW * NC) + tid * 4;
    float4 acc = make_float4(0.f, 0.f, 0.f, 0.f);
#pragma unroll 4
    for (int p = 0; p < NP; ++p) {
        int4 off = sIdx[p]; float4 w = sWv[p];
        float4 f00 = *(const float4*)(Fb + off.x);
        float4 f01 = *(const float4*)(Fb + off.y);
        float4 f10 = *(const float4*)(Fb + off.z);
        float4 f11 = *(const float4*)(Fb + off.w);
        acc.x = fmaf(w.x, f00.x, fmaf(w.y, f01.x, fmaf(w.z, f10.x, fmaf(w.w, f11.x, acc.x))));
        acc.y = fmaf(w.x, f00.y, fmaf(w.y, f01.y, fmaf(w.z, f10.y, fmaf(w.w, f11.y, acc.y))));
        acc.z = fmaf(w.x, f00.z, fmaf(w.y, f01.z, fmaf(w.z, f10.z, fmaf(w.w, f11.z, acc.z))));
        acc.w = fmaf(w.x, f00.w, fmaf(w.y, f01.w, fmaf(w.z, f10.w, fmaf(w.w, f11.w, acc.w))));
    }
    const float inv = 1.0f / (float)NP;
    ((float4*)(out + (size_t)bid * NC))[tid] =
        make_float4(acc.x * inv, acc.y * inv, acc.z * inv, acc.w * inv);
}

extern "C" void kernel_launch(void* const* d_in, const int* in_sizes, int n_in,
                              void* d_out, int out_size, void* d_ws, size_t ws_size,
                              hipStream_t stream) {
    const float* fm = (const float*)d_in[0];   // [8, 4096, 1024]
    const float* pc = (const float*)d_in[1];   // [8, 32, 512, 2]
    float* out = (float*)d_out;                // [8, 32, 1, 1024]

    const size_t wbytes = (size_t)NB * NHW * NM * sizeof(float);           // 4 MB
    const size_t pbytes = (size_t)NKC * NB * NM * NC * sizeof(float);      // 32 MB
    if (ws_size >= wbytes + pbytes) {
        float* W = (float*)d_ws;
        float* P = (float*)((char*)d_ws + wbytes);
        hipMemsetAsync(W, 0, wbytes, stream);
        scatter_w<<<(NB * NM * NP) / 256, 256, 0, stream>>>(pc, W);
        dim3 grid(NKC, NCT, NB);
        wgemm<<<grid, 256, 0, stream>>>(W, fm, P);
        reduce_p<<<(NB * NM * NC / 4) / 256, 256, 0, stream>>>(P, out);
    } else {
        region_pool_direct<<<NB * NM, 256, 0, stream>>>(fm, pc, out);
    }
}